// Round 21
// baseline (53.782 us; speedup 1.0000x reference)
//
#include <hip/hip_runtime.h>
#include <cstdint>
#include <cmath>

#define D_DIM 2048
#define E_DIM 64
#define N_TOK 16384
#define K_TOP 8
#define KSTEP 32
#define NFRAG 12       // 4 etiles x 3 terms

typedef __attribute__((ext_vector_type(8))) short bf16x8;
typedef __attribute__((ext_vector_type(4))) float f32x4;

// round-to-nearest bf16 3-way split: x = h + m + l + r, |r| ~ 2^-23 |x|
__device__ inline void split3(const f32x4 v0, const f32x4 v1,
                              bf16x8& h, bf16x8& m, bf16x8& l) {
#pragma unroll
  for (int j = 0; j < 8; ++j) {
    const float x = (j < 4) ? v0[j] : v1[j - 4];
    const unsigned u = __builtin_bit_cast(unsigned, x);
    const unsigned rh = (u + 0x7FFFu + ((u >> 16) & 1u)) & 0xFFFF0000u;
    h[j] = (short)(rh >> 16);
    const float r1 = x - __builtin_bit_cast(float, rh);
    const unsigned u1 = __builtin_bit_cast(unsigned, r1);
    const unsigned rm = (u1 + 0x7FFFu + ((u1 >> 16) & 1u)) & 0xFFFF0000u;
    m[j] = (short)(rm >> 16);
    const float r2 = r1 - __builtin_bit_cast(float, rm);
    l[j] = (short)(__builtin_bit_cast(unsigned, r2) >> 16);
  }
}

// Kernel 1: pre-split W into 3-term MFMA B-fragments.
__global__ void wprep_kernel(const float* __restrict__ W, uint4* __restrict__ WF) {
  const int gid = blockIdx.x * 256 + threadIdx.x;
  const int lane = gid & 63;
  const int et = (gid >> 6) & 3;
  const int ks = gid >> 8;  // 0..63 global k-step
  const int e = et * 16 + (lane & 15);
  const int kg = lane >> 4;
  const float* src = W + (size_t)e * D_DIM + ks * KSTEP + kg * 8;
  const f32x4 a = *(const f32x4*)src;
  const f32x4 b = *(const f32x4*)(src + 4);
  bf16x8 h, m, l;
  split3(a, b, h, m, l);
  const int fbase = (ks * NFRAG + et * 3) * 64 + lane;
  WF[fbase] = __builtin_bit_cast(uint4, h);
  WF[fbase + 64] = __builtin_bit_cast(uint4, m);
  WF[fbase + 128] = __builtin_bit_cast(uint4, l);
}

#define BCV(x) __builtin_bit_cast(bf16x8, x)
#define MM(d, A, B) d = __builtin_amdgcn_mfma_f32_16x16x32_bf16(A, BCV(B), d, 0, 0, 0)

#define GL4(dst, voff, sbase, IMM)                              \
  asm volatile("global_load_dwordx4 %0, %1, %2 offset:" #IMM    \
               : "=v"(dst) : "v"(voff), "s"(sbase) : "memory")

#define SB0 __builtin_amdgcn_sched_barrier(0)
#define WAITV(N) asm volatile("s_waitcnt vmcnt(" #N ")" ::: "memory")
#define WAITL0 asm volatile("s_waitcnt lgkmcnt(0)" ::: "memory")
#define FENCE asm volatile("" ::: "memory")
#define BAR __builtin_amdgcn_s_barrier()

// Kernel A: 1024 blocks x 4 waves, 3 blocks/CU (LDS-capped), 12 waves/CU.
// Block = 64 tokens x K-slice 512 (4 phases x 4 steps). Schedule identical to
// r18 (phase-batched B via asm regs -> ds_write; barrier-free steps; order
// always waitv -> CRUNCH(consume) -> LOADX(refill)), with M halved: 1 A-tile
// per wave, 24 MFMA/step, 2-load X steps.
__global__ __launch_bounds__(256, 3)
void gemm_partial(const float* __restrict__ X, const uint4* __restrict__ WF,
                  float* __restrict__ Part) {
  __shared__ uint4 ldsB[4][NFRAG][64];  // one phase: 4 steps x 12 frags = 48 KB

  const int bid = blockIdx.x;   // 1024
  const int ks = bid & 3;       // k-slice
  const int mtile = bid >> 2;   // 0..255 : 64-token tile
  const int tid = threadIdx.x;
  const int w = tid >> 6;
  const int l = tid & 63;
  const int col = l & 15;
  const int kg = l >> 4;
  const int w3 = w * 3;
  const int tokw = mtile * 64 + w * 16;  // this wave's 16 tokens

  const char* sX = (const char*)X + (size_t)(mtile * 64) * 8192 + (size_t)ks * 2048;
  const char* wfB = (const char*)WF + (size_t)ks * 16 * 12288;  // 16 steps/slice

  const unsigned vX0 = (unsigned)(w * 16 * 8192 + col * 8192 + kg * 32);
  const unsigned voffB = (unsigned)(w3 * 1024 + l * 16);

  f32x4 acc0[4], acc1[4];  // [et]
#pragma unroll
  for (int i = 0; i < 4; ++i) { acc0[i] = (f32x4)0.f; acc1[i] = (f32x4)0.f; }

  f32x4 xE[2], xO[2];
  uint4 bP[12];  // phase-B staging regs (asm-forced live)

#define LOADX(xS, g)                          \
  do {                                        \
    const char* sX_ = sX + (size_t)(g) * 128; \
    GL4(xS[0], vX0, sX_, 0);                  \
    GL4(xS[1], vX0, sX_, 16);                 \
  } while (0)

#define ISSUE_B(ph)                                            \
  do {                                                         \
    const char* sb_ = wfB + (size_t)(ph) * 49152;              \
    GL4(bP[0], voffB, sb_, 0);                                 \
    GL4(bP[1], voffB, sb_, 1024);                              \
    GL4(bP[2], voffB, sb_, 2048);                              \
    const char* s1_ = sb_ + 12288;                             \
    GL4(bP[3], voffB, s1_, 0);                                 \
    GL4(bP[4], voffB, s1_, 1024);                              \
    GL4(bP[5], voffB, s1_, 2048);                              \
    const char* s2_ = sb_ + 24576;                             \
    GL4(bP[6], voffB, s2_, 0);                                 \
    GL4(bP[7], voffB, s2_, 1024);                              \
    GL4(bP[8], voffB, s2_, 2048);                              \
    const char* s3_ = sb_ + 36864;                             \
    GL4(bP[9], voffB, s3_, 0);                                 \
    GL4(bP[10], voffB, s3_, 1024);                             \
    GL4(bP[11], voffB, s3_, 2048);                             \
  } while (0)

#define DSW                                   \
  do {                                        \
    ldsB[0][w3 + 0][l] = bP[0];               \
    ldsB[0][w3 + 1][l] = bP[1];               \
    ldsB[0][w3 + 2][l] = bP[2];               \
    ldsB[1][w3 + 0][l] = bP[3];               \
    ldsB[1][w3 + 1][l] = bP[4];               \
    ldsB[1][w3 + 2][l] = bP[5];               \
    ldsB[2][w3 + 0][l] = bP[6];               \
    ldsB[2][w3 + 1][l] = bP[7];               \
    ldsB[2][w3 + 2][l] = bP[8];               \
    ldsB[3][w3 + 0][l] = bP[9];               \
    ldsB[3][w3 + 1][l] = bP[10];              \
    ldsB[3][w3 + 2][l] = bP[11];              \
  } while (0)

  // 24 MFMAs, h/m/l-phased (one A-tile)
#define CRUNCH(s, xS)                                                              \
  do {                                                                             \
    bf16x8 ah, am, al;                                                             \
    split3(xS[0], xS[1], ah, am, al);                                              \
    const uint4* fb_ = &ldsB[s][0][0];                                             \
    {                                                                              \
      uint4 hh0 = fb_[0 * 64 + l], hh1 = fb_[3 * 64 + l];                          \
      uint4 hh2 = fb_[6 * 64 + l], hh3 = fb_[9 * 64 + l];                          \
      MM(acc0[0], ah, hh0); MM(acc0[1], ah, hh1);                                  \
      MM(acc0[2], ah, hh2); MM(acc0[3], ah, hh3);                                  \
      MM(acc1[0], am, hh0); MM(acc1[1], am, hh1);                                  \
      MM(acc1[2], am, hh2); MM(acc1[3], am, hh3);                                  \
      MM(acc1[0], al, hh0); MM(acc1[1], al, hh1);                                  \
      MM(acc1[2], al, hh2); MM(acc1[3], al, hh3);                                  \
    }                                                                              \
    {                                                                              \
      uint4 mm0 = fb_[1 * 64 + l], mm1 = fb_[4 * 64 + l];                          \
      uint4 mm2 = fb_[7 * 64 + l], mm3 = fb_[10 * 64 + l];                         \
      MM(acc1[0], ah, mm0); MM(acc1[1], ah, mm1);                                  \
      MM(acc1[2], ah, mm2); MM(acc1[3], ah, mm3);                                  \
      MM(acc1[0], am, mm0); MM(acc1[1], am, mm1);                                  \
      MM(acc1[2], am, mm2); MM(acc1[3], am, mm3);                                  \
    }                                                                              \
    {                                                                              \
      uint4 ll0 = fb_[2 * 64 + l], ll1 = fb_[5 * 64 + l];                          \
      uint4 ll2 = fb_[8 * 64 + l], ll3 = fb_[11 * 64 + l];                         \
      MM(acc1[0], ah, ll0); MM(acc1[1], ah, ll1);                                  \
      MM(acc1[2], ah, ll2); MM(acc1[3], ah, ll3);                                  \
    }                                                                              \
  } while (0)

  // prologue: B(0) 12 + X0 2 + X1 2 = 16 outstanding
  ISSUE_B(0);
  LOADX(xE, 0);
  LOADX(xO, 1);

#pragma unroll 1
  for (int p = 0; p < 3; ++p) {  // phases 0..2 (phase 3 = tail)
    const int g0 = p * 4;
    FENCE; BAR; FENCE;           // all waves done reading previous phase LDS
    WAITV(4); SB0;               // retire B(p) regs; X(g0),X(g0+1) remain (4)
    DSW;
    WAITL0; SB0;
    FENCE; BAR; FENCE;           // phase buffer ready for all waves
    ISSUE_B(p + 1);              // queue: X(g0)2, X(g0+1)2, B(p+1)12 = 16
    WAITV(14); SB0;              // retire X(g0)
    CRUNCH(0, xE);
    LOADX(xE, g0 + 2);           // queue: X(g0+1)2, B12, X(g0+2)2 = 16
    WAITV(14); SB0;              // retire X(g0+1)
    CRUNCH(1, xO);
    LOADX(xO, g0 + 3);           // queue: B12, X(g0+2)2, X(g0+3)2 = 16
    WAITV(2); SB0;               // retire B(p+1) + X(g0+2)
    CRUNCH(2, xE);
    LOADX(xE, g0 + 4);           // queue: X(g0+3)2, X(g0+4)2 = 4
    WAITV(2); SB0;               // retire X(g0+3)
    CRUNCH(3, xO);
    LOADX(xO, g0 + 5);           // queue: X(g0+4)2, X(g0+5)2 = 4
  }
  // phase 3 tail (steps 12..15); B(3) regs retired at p=2 q2
  FENCE; BAR; FENCE;
  WAITV(4); SB0;                 // no-op (4 outstanding), ledger explicit
  DSW;
  WAITL0; SB0;
  FENCE; BAR; FENCE;
  WAITV(2); SB0;                 // retire X12
  CRUNCH(0, xE);
  LOADX(xE, 14);                 // queue: X13 2, X14 2 = 4
  WAITV(2); SB0;                 // retire X13
  CRUNCH(1, xO);
  LOADX(xO, 15);                 // queue: X14 2, X15 2 = 4
  WAITV(2); SB0;                 // retire X14
  CRUNCH(2, xE);
  WAITV(0); SB0;                 // retire X15
  CRUNCH(3, xO);

  // write partials: Part[ks][tok][e]; C/D layout col=lane&15, row=(lane>>4)*4+q
#pragma unroll
  for (int q = 0; q < 4; ++q) {
    const int tok = tokw + kg * 4 + q;
    float* dst = Part + ((size_t)ks * N_TOK + tok) * E_DIM + col;
#pragma unroll
    for (int et = 0; et < 4; ++et)
      dst[et * 16] = acc0[et][q] + acc1[et][q];
  }
}

// Kernel B: fixed-order 4-way reduce + validated ballot top-8 + softmax + scatter.
__global__ __launch_bounds__(256)
void reduce_router(const float* __restrict__ Part,
                   float* __restrict__ Pout, float* __restrict__ Mout) {
  const int lane = threadIdx.x & 63;
  const int gw = blockIdx.x * 4 + (threadIdx.x >> 6);  // 4096 waves

#pragma unroll 1
  for (int j = 0; j < 4; ++j) {
    const int tok = gw * 4 + j;
    const size_t base = (size_t)tok * E_DIM + lane;
    float v = Part[base];
    v += Part[(size_t)1 * N_TOK * E_DIM + base];
    v += Part[(size_t)2 * N_TOK * E_DIM + base];
    v += Part[(size_t)3 * N_TOK * E_DIM + base];

    float topv[K_TOP];
    int topi[K_TOP];
#pragma unroll
    for (int kk = 0; kk < K_TOP; ++kk) {
      float m = v;
#pragma unroll
      for (int off = 32; off > 0; off >>= 1)
        m = fmaxf(m, __shfl_xor(m, off, 64));
      const unsigned long long bal = __ballot(v == m);
      const int li = __ffsll(bal) - 1;  // lowest expert on ties == jax stable order
      topv[kk] = m;
      topi[kk] = li;
      if (lane == li) v = -INFINITY;
    }

    float p[K_TOP], sum = 0.f;
#pragma unroll
    for (int kk = 0; kk < K_TOP; ++kk) {
      p[kk] = expf(topv[kk] - topv[0]);
      sum += p[kk];
    }
    const float inv = 1.f / sum;

    float pv = 0.f, mv = 0.f;
#pragma unroll
    for (int kk = 0; kk < K_TOP; ++kk)
      if (topi[kk] == lane) { pv = p[kk] * inv; mv = 1.f; }

    Pout[(size_t)tok * E_DIM + lane] = pv;
    Mout[(size_t)tok * E_DIM + lane] = mv;
  }
}

extern "C" void kernel_launch(void* const* d_in, const int* in_sizes, int n_in,
                              void* d_out, int out_size, void* d_ws, size_t ws_size,
                              hipStream_t stream) {
  const float* X = (const float*)d_in[0];
  const float* W = (const float*)d_in[1];
  float* P = (float*)d_out;
  float* M = P + (size_t)N_TOK * E_DIM;

  uint4* WF = (uint4*)d_ws;                                 // 768 KB at offset 0
  float* Part = (float*)((char*)d_ws + (size_t)(1 << 20));  // 16 MB at offset 1 MB

  wprep_kernel<<<dim3(64), dim3(256), 0, stream>>>(W, WF);
  gemm_partial<<<dim3(1024), dim3(256), 0, stream>>>(X, WF, Part);
  reduce_router<<<dim3(1024), dim3(256), 0, stream>>>(Part, P, M);
}

// Round 22
// 51.362 us; speedup vs baseline: 1.0471x; 1.0471x over previous
//
#include <hip/hip_runtime.h>
#include <cstdint>
#include <cmath>

#define D_DIM 2048
#define E_DIM 64
#define N_TOK 16384
#define K_TOP 8
#define KSTEP 32
#define NFRAG 12       // 4 etiles x 3 terms

typedef __attribute__((ext_vector_type(8))) short bf16x8;
typedef __attribute__((ext_vector_type(4))) float f32x4;

// round-to-nearest bf16 3-way split: x = h + m + l + r, |r| ~ 2^-23 |x|
__device__ inline void split3(const f32x4 v0, const f32x4 v1,
                              bf16x8& h, bf16x8& m, bf16x8& l) {
#pragma unroll
  for (int j = 0; j < 8; ++j) {
    const float x = (j < 4) ? v0[j] : v1[j - 4];
    const unsigned u = __builtin_bit_cast(unsigned, x);
    const unsigned rh = (u + 0x7FFFu + ((u >> 16) & 1u)) & 0xFFFF0000u;
    h[j] = (short)(rh >> 16);
    const float r1 = x - __builtin_bit_cast(float, rh);
    const unsigned u1 = __builtin_bit_cast(unsigned, r1);
    const unsigned rm = (u1 + 0x7FFFu + ((u1 >> 16) & 1u)) & 0xFFFF0000u;
    m[j] = (short)(rm >> 16);
    const float r2 = r1 - __builtin_bit_cast(float, rm);
    l[j] = (short)(__builtin_bit_cast(unsigned, r2) >> 16);
  }
}

// Kernel 1: pre-split W into 3-term MFMA B-fragments.
__global__ void wprep_kernel(const float* __restrict__ W, uint4* __restrict__ WF) {
  const int gid = blockIdx.x * 256 + threadIdx.x;
  const int lane = gid & 63;
  const int et = (gid >> 6) & 3;
  const int ks = gid >> 8;  // 0..63 global k-step
  const int e = et * 16 + (lane & 15);
  const int kg = lane >> 4;
  const float* src = W + (size_t)e * D_DIM + ks * KSTEP + kg * 8;
  const f32x4 a = *(const f32x4*)src;
  const f32x4 b = *(const f32x4*)(src + 4);
  bf16x8 h, m, l;
  split3(a, b, h, m, l);
  const int fbase = (ks * NFRAG + et * 3) * 64 + lane;
  WF[fbase] = __builtin_bit_cast(uint4, h);
  WF[fbase + 64] = __builtin_bit_cast(uint4, m);
  WF[fbase + 128] = __builtin_bit_cast(uint4, l);
}

#define BCV(x) __builtin_bit_cast(bf16x8, x)
#define MM(d, A, B) d = __builtin_amdgcn_mfma_f32_16x16x32_bf16(A, BCV(B), d, 0, 0, 0)

#define GL4(dst, voff, sbase, IMM)                              \
  asm volatile("global_load_dwordx4 %0, %1, %2 offset:" #IMM    \
               : "=v"(dst) : "v"(voff), "s"(sbase) : "memory")

#define SB0 __builtin_amdgcn_sched_barrier(0)
#define WAITV(N) asm volatile("s_waitcnt vmcnt(" #N ")" ::: "memory")
#define WAITL0 asm volatile("s_waitcnt lgkmcnt(0)" ::: "memory")
#define FENCE asm volatile("" ::: "memory")
#define BAR __builtin_amdgcn_s_barrier()

// Kernel A: 512 blocks x 4 waves (r18 schedule, byte-identical). XCD-locality
// bid decode: ks = bid>>7, mtile = bid&127 -> the 4 k-slice blocks of one
// mtile are {m, m+128, m+256, m+384}, all == m (mod 8) -> same XCD -> X rows
// fetched once per XCD, later blocks hit L2.
__global__ __launch_bounds__(256, 2)
void gemm_partial(const float* __restrict__ X, const uint4* __restrict__ WF,
                  float* __restrict__ Part) {
  __shared__ uint4 ldsB[4][NFRAG][64];  // one phase: 4 steps x 12 frags = 48 KB

  const int bid = blockIdx.x;   // 512
  const int ks = bid >> 7;      // k-slice 0..3 (XCD-locality decode)
  const int mtile = bid & 127;  // 0..127 : 128-token tile
  const int tid = threadIdx.x;
  const int w = tid >> 6;
  const int l = tid & 63;
  const int col = l & 15;
  const int kg = l >> 4;
  const int w3 = w * 3;
  const int tokw = mtile * 128 + w * 32;

  const char* sX = (const char*)X + (size_t)(mtile * 128) * 8192 + (size_t)ks * 2048;
  const char* wfB = (const char*)WF + (size_t)ks * 16 * 12288;  // 16 steps/slice

  const unsigned vX0 = (unsigned)(w * 32 * 8192 + col * 8192 + kg * 32);
  const unsigned vX1 = vX0 + 16 * 8192;
  const unsigned voffB = (unsigned)(w3 * 1024 + l * 16);

  f32x4 acc0[8], acc1[8];
#pragma unroll
  for (int i = 0; i < 8; ++i) { acc0[i] = (f32x4)0.f; acc1[i] = (f32x4)0.f; }

  f32x4 xE[4], xO[4];
  uint4 bP[12];  // phase-B staging regs (asm-forced live)

#define LOADX(xS, g)                          \
  do {                                        \
    const char* sX_ = sX + (size_t)(g) * 128; \
    GL4(xS[0], vX0, sX_, 0);                  \
    GL4(xS[1], vX0, sX_, 16);                 \
    GL4(xS[2], vX1, sX_, 0);                  \
    GL4(xS[3], vX1, sX_, 16);                 \
  } while (0)

#define ISSUE_B(ph)                                            \
  do {                                                         \
    const char* sb_ = wfB + (size_t)(ph) * 49152;              \
    GL4(bP[0], voffB, sb_, 0);                                 \
    GL4(bP[1], voffB, sb_, 1024);                              \
    GL4(bP[2], voffB, sb_, 2048);                              \
    const char* s1_ = sb_ + 12288;                             \
    GL4(bP[3], voffB, s1_, 0);                                 \
    GL4(bP[4], voffB, s1_, 1024);                              \
    GL4(bP[5], voffB, s1_, 2048);                              \
    const char* s2_ = sb_ + 24576;                             \
    GL4(bP[6], voffB, s2_, 0);                                 \
    GL4(bP[7], voffB, s2_, 1024);                              \
    GL4(bP[8], voffB, s2_, 2048);                              \
    const char* s3_ = sb_ + 36864;                             \
    GL4(bP[9], voffB, s3_, 0);                                 \
    GL4(bP[10], voffB, s3_, 1024);                             \
    GL4(bP[11], voffB, s3_, 2048);                             \
  } while (0)

#define DSW                                   \
  do {                                        \
    ldsB[0][w3 + 0][l] = bP[0];               \
    ldsB[0][w3 + 1][l] = bP[1];               \
    ldsB[0][w3 + 2][l] = bP[2];               \
    ldsB[1][w3 + 0][l] = bP[3];               \
    ldsB[1][w3 + 1][l] = bP[4];               \
    ldsB[1][w3 + 2][l] = bP[5];               \
    ldsB[2][w3 + 0][l] = bP[6];               \
    ldsB[2][w3 + 1][l] = bP[7];               \
    ldsB[2][w3 + 2][l] = bP[8];               \
    ldsB[3][w3 + 0][l] = bP[9];               \
    ldsB[3][w3 + 1][l] = bP[10];              \
    ldsB[3][w3 + 2][l] = bP[11];              \
  } while (0)

#define CRUNCH(s, xS)                                                              \
  do {                                                                             \
    bf16x8 ah0, am0, al0, ah1, am1, al1;                                           \
    split3(xS[0], xS[1], ah0, am0, al0);                                           \
    split3(xS[2], xS[3], ah1, am1, al1);                                           \
    const uint4* fb_ = &ldsB[s][0][0];                                             \
    {                                                                              \
      uint4 hh0 = fb_[0 * 64 + l], hh1 = fb_[3 * 64 + l];                          \
      uint4 hh2 = fb_[6 * 64 + l], hh3 = fb_[9 * 64 + l];                          \
      MM(acc0[0], ah0, hh0); MM(acc0[4], ah1, hh0);                                \
      MM(acc0[1], ah0, hh1); MM(acc0[5], ah1, hh1);                                \
      MM(acc0[2], ah0, hh2); MM(acc0[6], ah1, hh2);                                \
      MM(acc0[3], ah0, hh3); MM(acc0[7], ah1, hh3);                                \
      MM(acc1[0], am0, hh0); MM(acc1[4], am1, hh0);                                \
      MM(acc1[1], am0, hh1); MM(acc1[5], am1, hh1);                                \
      MM(acc1[2], am0, hh2); MM(acc1[6], am1, hh2);                                \
      MM(acc1[3], am0, hh3); MM(acc1[7], am1, hh3);                                \
      MM(acc1[0], al0, hh0); MM(acc1[4], al1, hh0);                                \
      MM(acc1[1], al0, hh1); MM(acc1[5], al1, hh1);                                \
      MM(acc1[2], al0, hh2); MM(acc1[6], al1, hh2);                                \
      MM(acc1[3], al0, hh3); MM(acc1[7], al1, hh3);                                \
    }                                                                              \
    {                                                                              \
      uint4 mm0 = fb_[1 * 64 + l], mm1 = fb_[4 * 64 + l];                          \
      uint4 mm2 = fb_[7 * 64 + l], mm3 = fb_[10 * 64 + l];                         \
      MM(acc1[0], ah0, mm0); MM(acc1[4], ah1, mm0);                                \
      MM(acc1[1], ah0, mm1); MM(acc1[5], ah1, mm1);                                \
      MM(acc1[2], ah0, mm2); MM(acc1[6], ah1, mm2);                                \
      MM(acc1[3], ah0, mm3); MM(acc1[7], ah1, mm3);                                \
      MM(acc1[0], am0, mm0); MM(acc1[4], am1, mm0);                                \
      MM(acc1[1], am0, mm1); MM(acc1[5], am1, mm1);                                \
      MM(acc1[2], am0, mm2); MM(acc1[6], am1, mm2);                                \
      MM(acc1[3], am0, mm3); MM(acc1[7], am1, mm3);                                \
    }                                                                              \
    {                                                                              \
      uint4 ll0 = fb_[2 * 64 + l], ll1 = fb_[5 * 64 + l];                          \
      uint4 ll2 = fb_[8 * 64 + l], ll3 = fb_[11 * 64 + l];                         \
      MM(acc1[0], ah0, ll0); MM(acc1[4], ah1, ll0);                                \
      MM(acc1[1], ah0, ll1); MM(acc1[5], ah1, ll1);                                \
      MM(acc1[2], ah0, ll2); MM(acc1[6], ah1, ll2);                                \
      MM(acc1[3], ah0, ll3); MM(acc1[7], ah1, ll3);                                \
    }                                                                              \
  } while (0)

  // prologue: B(0) 12 + X0 4 + X1 4 = 20 outstanding
  ISSUE_B(0);
  LOADX(xE, 0);
  LOADX(xO, 1);

#pragma unroll 1
  for (int p = 0; p < 3; ++p) {  // phases 0..2 (phase 3 = tail)
    const int g0 = p * 4;
    FENCE; BAR; FENCE;           // all waves done reading previous phase LDS
    WAITV(8); SB0;               // retire B(p) regs; X(g0),X(g0+1) remain
    DSW;
    WAITL0; SB0;
    FENCE; BAR; FENCE;           // phase buffer ready for all waves
    ISSUE_B(p + 1);              // queue: X(g0)4, X(g0+1)4, B(p+1)12 = 20
    WAITV(16); SB0;              // retire X(g0)
    CRUNCH(0, xE);
    LOADX(xE, g0 + 2);
    WAITV(16); SB0;              // retire X(g0+1)
    CRUNCH(1, xO);
    LOADX(xO, g0 + 3);
    WAITV(4); SB0;               // retire B(p+1) + X(g0+2)
    CRUNCH(2, xE);
    LOADX(xE, g0 + 4);
    WAITV(4); SB0;               // retire X(g0+3)
    CRUNCH(3, xO);
    LOADX(xO, g0 + 5);
  }
  // phase 3 tail (steps 12..15)
  FENCE; BAR; FENCE;
  WAITV(8); SB0;
  DSW;
  WAITL0; SB0;
  FENCE; BAR; FENCE;
  WAITV(4); SB0;                 // retire X12
  CRUNCH(0, xE);
  LOADX(xE, 14);
  WAITV(4); SB0;                 // retire X13
  CRUNCH(1, xO);
  LOADX(xO, 15);
  WAITV(4); SB0;                 // retire X14
  CRUNCH(2, xE);
  WAITV(0); SB0;                 // retire X15
  CRUNCH(3, xO);

  // write partials: Part[ks][tok][e]; C/D layout col=lane&15, row=(lane>>4)*4+q
#pragma unroll
  for (int half = 0; half < 2; ++half)
#pragma unroll
    for (int q = 0; q < 4; ++q) {
      const int tok = tokw + half * 16 + kg * 4 + q;
      float* dst = Part + ((size_t)ks * N_TOK + tok) * E_DIM + col;
#pragma unroll
      for (int et = 0; et < 4; ++et)
        dst[et * 16] = acc0[half * 4 + et][q] + acc1[half * 4 + et][q];
    }
}

// Kernel B: fixed-order 4-way reduce + validated ballot top-8 + softmax + scatter.
__global__ __launch_bounds__(256)
void reduce_router(const float* __restrict__ Part,
                   float* __restrict__ Pout, float* __restrict__ Mout) {
  const int lane = threadIdx.x & 63;
  const int gw = blockIdx.x * 4 + (threadIdx.x >> 6);  // 4096 waves

#pragma unroll 1
  for (int j = 0; j < 4; ++j) {
    const int tok = gw * 4 + j;
    const size_t base = (size_t)tok * E_DIM + lane;
    float v = Part[base];
    v += Part[(size_t)1 * N_TOK * E_DIM + base];
    v += Part[(size_t)2 * N_TOK * E_DIM + base];
    v += Part[(size_t)3 * N_TOK * E_DIM + base];

    float topv[K_TOP];
    int topi[K_TOP];
#pragma unroll
    for (int kk = 0; kk < K_TOP; ++kk) {
      float m = v;
#pragma unroll
      for (int off = 32; off > 0; off >>= 1)
        m = fmaxf(m, __shfl_xor(m, off, 64));
      const unsigned long long bal = __ballot(v == m);
      const int li = __ffsll(bal) - 1;  // lowest expert on ties == jax stable order
      topv[kk] = m;
      topi[kk] = li;
      if (lane == li) v = -INFINITY;
    }

    float p[K_TOP], sum = 0.f;
#pragma unroll
    for (int kk = 0; kk < K_TOP; ++kk) {
      p[kk] = expf(topv[kk] - topv[0]);
      sum += p[kk];
    }
    const float inv = 1.f / sum;

    float pv = 0.f, mv = 0.f;
#pragma unroll
    for (int kk = 0; kk < K_TOP; ++kk)
      if (topi[kk] == lane) { pv = p[kk] * inv; mv = 1.f; }

    Pout[(size_t)tok * E_DIM + lane] = pv;
    Mout[(size_t)tok * E_DIM + lane] = mv;
  }
}

extern "C" void kernel_launch(void* const* d_in, const int* in_sizes, int n_in,
                              void* d_out, int out_size, void* d_ws, size_t ws_size,
                              hipStream_t stream) {
  const float* X = (const float*)d_in[0];
  const float* W = (const float*)d_in[1];
  float* P = (float*)d_out;
  float* M = P + (size_t)N_TOK * E_DIM;

  uint4* WF = (uint4*)d_ws;                                 // 768 KB at offset 0
  float* Part = (float*)((char*)d_ws + (size_t)(1 << 20));  // 16 MB at offset 1 MB

  wprep_kernel<<<dim3(64), dim3(256), 0, stream>>>(W, WF);
  gemm_partial<<<dim3(512), dim3(256), 0, stream>>>(X, WF, Part);
  reduce_router<<<dim3(1024), dim3(256), 0, stream>>>(Part, P, M);
}